// Round 2
// baseline (2394.590 us; speedup 1.0000x reference)
//
#include <hip/hip_runtime.h>
#include <hip/hip_bf16.h>

// TimeLSTM: B=2048, T=256, IN=65 (1 time-delta + 64 features), H=256, gates=1024.
//
// Round 7: kill the serial L2-stream stall with an LDS staging ring.
// r6 post-mortem: 17K cy/step, ~80% stall; 2 waves/SIMD stall in lockstep on
// 16 sequential 2-frag L2 loads with only ~40cy lookahead (VGPR-capped depth).
// Changes:
//  - W kt4..9 streamed via global_load_lds into a 4 x 32KB LDS ring (depth 3
//    in flight), 12 half-kt phases/step. In-flight data costs 0 VGPRs.
//  - Hand-counted s_waitcnt vmcnt(N) per phase (never 0 in loop); raw
//    "lgkmcnt(0); s_barrier" step barrier so refills stay in flight ACROSS
//    the barrier (issued phases 9..11 for next step, consumed phases 0..2).
//  - x(t+1) prefetch = exactly 3 inline-asm global_load_dword at a fixed
//    FIFO slot (start of step, after prev step's ph9..11 refills) so vmcnt
//    constants are exact: ph0..2 wait 11 (2 chunks + 3 x), ph3..11 wait 8.
//  - Refill at phase p targets buffer (p+3)&3 = freed one phase earlier
//    (never the buffer being read this phase).
// Tiers per wave: kt 0..3 AGPR (128 AGPRs via "a"-pinned MFMA), kt 4..9
// streamed (384KB/CU/step through L2+LDS). VGPR side ~<=110 -> 2 waves/SIMD.
// C/D layout (m89): col = lane&15, row = (lane>>4)*4 + reg. Wave w owns cols
// w*32 + jt*16 + l15 (jt=0,1); all 4 gates of a column in one lane.

typedef __bf16 v8bf __attribute__((ext_vector_type(8)));
typedef __bf16 v2bf __attribute__((ext_vector_type(2)));
typedef float f32x4 __attribute__((ext_vector_type(4)));
typedef int   v4i  __attribute__((ext_vector_type(4)));
typedef unsigned int u32;

#define B_SZ 2048
#define T_SZ 256
#define IN_SZ 65
#define MBLK 16
#define NBLOCKS (B_SZ / MBLK)   // 128
#define THREADS 512
#define NW 8

#define WREG_KT 4               // kt 0..3 in AGPRs (128 AGPR/wave)
#define SKT0 4                  // first streamed kt
#define NKT 10
#define FRAGS 8                 // frags per (kt, wave): 4 gates x 2 col-tiles
#define STG_BUF 32768           // one half-kt chunk buffer (8 waves x 4 frags x 1KB)
#define STG_BYTES (4 * STG_BUF) // 131072
#define A_STRIDE 344            // bf16 elems; 688B rows: 16B-aligned
#define A_BYTES (16 * A_STRIDE * 2)        // 11008
#define A0_OFF STG_BYTES
#define A1_OFF (A0_OFF + A_BYTES)
#define TD_OFF (A1_OFF + A_BYTES)          // 153088
#define OUT_OFF (TD_OFF + 128)             // 153216
#define SMEM_TOTAL (OUT_OFF + 64)          // 153280 <= 160K

__device__ __forceinline__ float fsig(float xv) {
    return __builtin_amdgcn_rcpf(1.f + __expf(-xv));
}
__device__ __forceinline__ float ftanh(float xv) {
    return fmaf(2.f, fsig(2.f * xv), -1.f);
}
// B operand pinned to AGPR ("a") -> W kt0..3 genuinely register-resident.
__device__ __forceinline__ void mfma_a(f32x4& acc, v4i av, v4i bv) {
    asm("v_mfma_f32_16x16x32_bf16 %0, %1, %2, %0" : "+v"(acc) : "v"(av), "a"(bv));
}
__device__ __forceinline__ void mfma_v(f32x4& acc, v4i av, v4i bv) {
    asm("v_mfma_f32_16x16x32_bf16 %0, %1, %2, %0" : "+v"(acc) : "v"(av), "v"(bv));
}
// async 16B/lane global -> LDS (wave-uniform LDS base + lane*16; global src per-lane)
__device__ __forceinline__ void async_frag(const char* g, char* l) {
    __builtin_amdgcn_global_load_lds(
        (const __attribute__((address_space(1))) u32*)g,
        (__attribute__((address_space(3))) u32*)l, 16, 0, 0);
}
// W fragment pointer for AGPR prologue loads (elems; wsz_w folds lane*8 + w*4096)
__device__ __forceinline__ const v4i* wfrag(const __bf16* wsz_w, int kt, int i) {
    return reinterpret_cast<const v4i*>(wsz_w + kt * 32768 + i * 512);
}

#define VMW(n) asm volatile("s_waitcnt vmcnt(" #n ")" ::: "memory")
#define BARRIER() asm volatile("s_waitcnt lgkmcnt(0)\n\ts_barrier" ::: "memory")

// ---------------- prep: swizzle W into MFMA B-fragment order (bf16) ----------------
// 640 fragments (kt 0..9, w 0..7, i 0..7), 1KB each: 640KB in d_ws.
// frag(kt,w,i): lane L holds W[n][k], n = (i>>1)*256 + w*32 + (i&1)*16 + (L&15),
//               k = kt*32 + (L>>4)*8 + j, j=0..7.
__global__ void prep_w(const float* __restrict__ W_ih, const float* __restrict__ W_hh,
                       __bf16* __restrict__ wsz) {
    int gtid = blockIdx.x * 256 + threadIdx.x;   // 0..40959
    int lane = gtid & 63;
    int frag = gtid >> 6;                        // 0..639
    int kt = frag >> 6;
    int w  = (frag >> 3) & 7;
    int i  = frag & 7;
    int g = i >> 1, jt = i & 1;
    int n  = g * 256 + w * 32 + jt * 16 + (lane & 15);
    int k0 = kt * 32 + ((lane >> 4) << 3);
    v8bf v;
#pragma unroll
    for (int j = 0; j < 8; ++j) {
        int k = k0 + j;
        float f = (k < 64) ? W_ih[n * 64 + k] : W_hh[n * 256 + (k - 64)];
        v[j] = (__bf16)f;
    }
    *reinterpret_cast<v8bf*>(wsz + (size_t)frag * 512 + lane * 8) = v;
}

// ---------------- one stream phase (PH, KW literals) ----------------
// chunk PH: kt = 4 + PH/2, frags (PH&1)*4 .. +3, buffer PH&3.
// refill chunk (PH+3)%12 -> buffer (PH+3)&3 (freed >=1 phase ago).
#define PHASE(PH, KW)                                                           \
  do {                                                                          \
    VMW(KW);                                                                    \
    v4i b0 = *(const v4i*)(stg_rd + ((PH) & 3) * STG_BUF);                      \
    v4i b1 = *(const v4i*)(stg_rd + ((PH) & 3) * STG_BUF + 1024);               \
    v4i b2 = *(const v4i*)(stg_rd + ((PH) & 3) * STG_BUF + 2048);               \
    v4i b3 = *(const v4i*)(stg_rd + ((PH) & 3) * STG_BUF + 3072);               \
    {                                                                           \
      const int CN  = ((PH) + 3) % 12;                                          \
      const int ktn = SKT0 + (CN >> 1);                                         \
      const int ibn = (CN & 1) * 4;                                             \
      const char* gs = wszb + ktn * 65536 + ibn * 1024;                         \
      char* ld = stg_wr + (CN & 3) * STG_BUF;                                   \
      async_frag(gs, ld);                                                       \
      async_frag(gs + 1024, ld + 1024);                                         \
      async_frag(gs + 2048, ld + 2048);                                         \
      async_frag(gs + 3072, ld + 3072);                                         \
    }                                                                           \
    if (((PH) & 1) == 0 && (PH) < 10)                                           \
      a_nxt = *(const v4i*)(Ac + aoff + (SKT0 + (PH) / 2 + 1) * 32);            \
    __builtin_amdgcn_s_setprio(1);                                              \
    mfma_v(acc[((PH) & 1) * 4 + 0], a_cur, b0);                                 \
    mfma_v(acc[((PH) & 1) * 4 + 1], a_cur, b1);                                 \
    mfma_v(acc[((PH) & 1) * 4 + 2], a_cur, b2);                                 \
    mfma_v(acc[((PH) & 1) * 4 + 3], a_cur, b3);                                 \
    __builtin_amdgcn_s_setprio(0);                                              \
    if (((PH) & 1) == 1) a_cur = a_nxt;                                         \
  } while (0)

// ---------------- one timestep (PAR = t&1 compile-time) ----------------
#define TSTEP(PAR, LOAD_NEXT)                                                   \
  do {                                                                          \
    const __bf16* Ac = (PAR) ? A1 : A0;                                         \
    __bf16* An = (PAR) ? A0 : A1;                                               \
    const float* tdc = (PAR) ? td1 : td0;                                       \
    float* tdn = (PAR) ? td0 : td1;                                             \
    /* x(t+1): exactly 3 asm loads, oldest vmem slot of this step */            \
    float px0, px1, ptd;                                                        \
    {                                                                           \
      unsigned xo = (LOAD_NEXT) ? xoff : xoff - 260u;                           \
      asm volatile("global_load_dword %0, %3, off offset:4\n\t"                 \
                   "global_load_dword %1, %3, off offset:8\n\t"                 \
                   "global_load_dword %2, %4, off offset:0"                     \
                   : "=&v"(px0), "=&v"(px1), "=&v"(ptd)                         \
                   : "v"(xb2 + xo), "v"(xb + xo)                                \
                   : "memory");                                                 \
      if (LOAD_NEXT) xoff += 260u;                                              \
    }                                                                           \
    f32x4 tdv = *(const f32x4*)(tdc + lhi * 4);                                 \
    v4i a_cur = *(const v4i*)(Ac + aoff);                                       \
    v4i a_nxt;                                                                  \
    f32x4 acc[FRAGS];                                                           \
    _Pragma("unroll")                                                           \
    for (int i = 0; i < FRAGS; ++i) acc[i] = (f32x4){0.f, 0.f, 0.f, 0.f};       \
    /* kt 0..3 from AGPRs (32 MFMA; covers c0 tail + a-read latency) */         \
    _Pragma("unroll")                                                           \
    for (int kt = 0; kt < WREG_KT; ++kt) {                                      \
      a_nxt = *(const v4i*)(Ac + aoff + (kt + 1) * 32);                         \
      __builtin_amdgcn_s_setprio(1);                                            \
      _Pragma("unroll")                                                         \
      for (int i = 0; i < FRAGS; ++i) mfma_a(acc[i], a_cur, wreg[kt * FRAGS + i]); \
      __builtin_amdgcn_s_setprio(0);                                            \
      a_cur = a_nxt;                                                            \
    }                                                                           \
    /* 12 streamed half-kt phases; waits: ph0..2 = 2 chunks + 3 x = 11,  */     \
    /* ph3..11 = 2 chunks = 8 (x drains at ph3, ~600cy after issue)      */     \
    PHASE(0, 11); PHASE(1, 11); PHASE(2, 11); PHASE(3, 8);                      \
    PHASE(4, 8);  PHASE(5, 8);  PHASE(6, 8);  PHASE(7, 8);                      \
    PHASE(8, 8);  PHASE(9, 8);  PHASE(10, 8); PHASE(11, 8);                     \
    /* lane-local LSTM epilogue: 4 gates x 2 cols x 4 rows */                   \
    _Pragma("unroll")                                                           \
    for (int jt = 0; jt < 2; ++jt) {                                            \
      float wt_f = (float)wtp[jt], bt_f = (float)btp[jt];                       \
      _Pragma("unroll")                                                         \
      for (int r = 0; r < 4; ++r) {                                             \
        float pi = acc[0 + jt][r] + (float)biasp[0][jt];                        \
        float pf = acc[2 + jt][r] + (float)biasp[1][jt];                        \
        float pg = acc[4 + jt][r] + (float)biasp[2][jt];                        \
        float po = acc[6 + jt][r] + (float)biasp[3][jt];                        \
        float d  = fsig(fmaf(tdv[r], wt_f, bt_f));                              \
        float c  = cst[jt][r] * d;                                              \
        c = fsig(pf) * c + fsig(pi) * ftanh(pg);                                \
        cst[jt][r] = c;                                                         \
        float h = fsig(po) * ftanh(c);                                          \
        An[hoff + r * A_STRIDE + jt * 16] = (__bf16)h;                          \
      }                                                                         \
    }                                                                           \
    /* stage x(t+1) into next buffer (px drained at ph3) */                     \
    {                                                                           \
      v2bf vv; vv[0] = (__bf16)px0; vv[1] = (__bf16)px1;                        \
      *reinterpret_cast<v2bf*>(An + xsoff) = vv;                                \
      if (xc == 0) tdn[xr] = ptd;                                               \
    }                                                                           \
    BARRIER();   /* lgkmcnt(0)+s_barrier only: refills stay in flight */        \
  } while (0)

// ---------------- fused persistent scan ----------------
__global__ __launch_bounds__(THREADS, 2)
void tlstm_scan(
    const float* __restrict__ x, const __bf16* __restrict__ wsz,
    const float* __restrict__ b_ih, const float* __restrict__ b_hh,
    const float* __restrict__ Wt, const float* __restrict__ bt,
    const float* __restrict__ Wf, const float* __restrict__ bfp,
    float* __restrict__ out) {
    extern __shared__ char smem[];
    __bf16* A0 = reinterpret_cast<__bf16*>(smem + A0_OFF);
    __bf16* A1 = reinterpret_cast<__bf16*>(smem + A1_OFF);
    float* td0 = reinterpret_cast<float*>(smem + TD_OFF);
    float* td1 = td0 + 16;
    float* out_acc = reinterpret_cast<float*>(smem + OUT_OFF);

    const int tid  = threadIdx.x;
    const int lane = tid & 63;
    const int w    = tid >> 6;     // 0..7
    const int l15  = lane & 15;
    const int lhi  = lane >> 4;
    const int b0   = blockIdx.x * MBLK;

    const __bf16* wsz_w = wsz + lane * 8 + w * 4096;            // elems
    const char* wszb = (const char*)wsz + lane * 16 + w * 8192; // bytes (stream src)
    const char* stg_rd = smem + w * 4096 + lane * 16;           // staged frag reads
    char* stg_wr = smem + w * 4096;                             // uniform gl_lds dst

    // ---- one-time: W kt 0..3 -> wreg (pinned to AGPRs by mfma_a's "a" use)
    v4i wreg[WREG_KT * FRAGS];
#pragma unroll
    for (int kt = 0; kt < WREG_KT; ++kt)
#pragma unroll
        for (int i = 0; i < FRAGS; ++i)
            wreg[kt * FRAGS + i] = *wfrag(wsz_w, kt, i);

    // zero A0 (h(-1)=0); barrier before x0 staging (different threads write)
    for (int i2 = tid; i2 < 16 * A_STRIDE; i2 += THREADS) A0[i2] = (__bf16)0.f;
    if (tid < 16) out_acc[tid] = 0.f;
    __syncthreads();

    // per-lane epilogue constants, packed bf16 (error << tolerance)
    v2bf biasp[4], wtp, btp;
    {
        int c0 = w * 32 + l15, c1 = c0 + 16;
#pragma unroll
        for (int g = 0; g < 4; ++g) {
            biasp[g][0] = (__bf16)(b_ih[g * 256 + c0] + b_hh[g * 256 + c0]);
            biasp[g][1] = (__bf16)(b_ih[g * 256 + c1] + b_hh[g * 256 + c1]);
        }
        wtp[0] = (__bf16)Wt[c0]; wtp[1] = (__bf16)Wt[c1];
        btp[0] = (__bf16)bt[c0]; btp[1] = (__bf16)bt[c1];
    }

    float cst[2][4];   // fp32 cell state: [jt][reg]
#pragma unroll
    for (int jt = 0; jt < 2; ++jt)
#pragma unroll
        for (int r = 0; r < 4; ++r) cst[jt][r] = 0.f;

    // x staging geometry: 512 threads cover 16 rows x 32 pairs of 2 features
    const int xr = tid >> 5;   // row 0..15
    const int xc = tid & 31;   // feature pair 0..31
    const char* xb  = (const char*)x + (size_t)(b0 + xr) * T_SZ * IN_SZ * 4;
    const char* xb2 = xb + 8 * xc;
    unsigned xoff = IN_SZ * 4;   // byte offset of t=1 row-slice

    {   // stage x(t=0) directly (normal loads; data-dep waits)
        const float* p = (const float*)xb;
        float q0 = p[1 + 2 * xc], q1 = p[2 + 2 * xc], qd = p[0];
        v2bf vv; vv[0] = (__bf16)q0; vv[1] = (__bf16)q1;
        *reinterpret_cast<v2bf*>(A0 + xr * A_STRIDE + 2 * xc) = vv;
        if (xc == 0) td0[xr] = qd;
    }

    // per-lane address bases (elems)
    const int aoff  = l15 * A_STRIDE + lhi * 8;
    const int hoff  = (lhi * 4) * A_STRIDE + 64 + w * 32 + l15;
    const int xsoff = xr * A_STRIDE + xc * 2;

    // drain all prologue vmem, then prime the stream ring with chunks 0..2
    VMW(0);
#pragma unroll
    for (int c = 0; c < 3; ++c) {
        const int ktn = SKT0 + (c >> 1);
        const int ibn = (c & 1) * 4;
#pragma unroll
        for (int f = 0; f < 4; ++f)
            async_frag(wszb + ktn * 65536 + (ibn + f) * 1024,
                       stg_wr + c * STG_BUF + f * 1024);
    }
    __syncthreads();   // A0/td0 visible (also drains the primed chunks: one-time cost)

    for (int t2 = 0; t2 < T_SZ / 2; ++t2) {
        TSTEP(0, 1);
        TSTEP(1, (t2 != T_SZ / 2 - 1));
    }

    // ---- output: out[b] = h_T . Wf + bf  (h_T lives in A0 after t=255)
    {
        const int row = tid >> 5;         // 0..15
        const int ch  = tid & 31;         // 8-col chunk
        v8bf hv = *reinterpret_cast<const v8bf*>(A0 + row * A_STRIDE + 64 + ch * 8);
        float s = 0.f;
#pragma unroll
        for (int j = 0; j < 8; ++j) s = fmaf((float)hv[j], Wf[ch * 8 + j], s);
        atomicAdd(&out_acc[row], s);
    }
    __syncthreads();
    if (tid < 16) out[b0 + tid] = out_acc[tid] + bfp[0];
}

extern "C" void kernel_launch(void* const* d_in, const int* in_sizes, int n_in,
                              void* d_out, int out_size, void* d_ws, size_t ws_size,
                              hipStream_t stream) {
    const float* x    = (const float*)d_in[0];
    const float* W_ih = (const float*)d_in[1];
    const float* W_hh = (const float*)d_in[2];
    const float* b_ih = (const float*)d_in[3];
    const float* b_hh = (const float*)d_in[4];
    const float* Wt   = (const float*)d_in[5];
    const float* bt   = (const float*)d_in[6];
    const float* Wf   = (const float*)d_in[7];
    const float* bfp  = (const float*)d_in[8];
    float* out  = (float*)d_out;
    __bf16* wsz = (__bf16*)d_ws;   // 640KB of swizzled bf16 W

    (void)in_sizes; (void)n_in; (void)out_size; (void)ws_size;

    hipFuncSetAttribute(reinterpret_cast<const void*>(tlstm_scan),
                        hipFuncAttributeMaxDynamicSharedMemorySize, SMEM_TOTAL);

    prep_w<<<dim3(160), dim3(256), 0, stream>>>(W_ih, W_hh, wsz);
    tlstm_scan<<<dim3(NBLOCKS), dim3(THREADS), SMEM_TOTAL, stream>>>(
        x, wsz, b_ih, b_hh, Wt, bt, Wf, bfp, out);
}